// Round 1
// 862.616 us; speedup vs baseline: 1.8438x; 1.8438x over previous
//
#include <hip/hip_runtime.h>
#include <hip/hip_bf16.h>
#include <stdint.h>

typedef unsigned short u16;
typedef __attribute__((ext_vector_type(8))) short short8;
typedef __attribute__((ext_vector_type(4))) float floatx4;

#define T_NUM 16384
#define D_DIM 3072
#define O_DIM 3072
#define E_NUM 8
#define R_DIM 32
#define KA    (E_NUM * R_DIM)   // 256 augmented-K columns

__device__ __forceinline__ float bf2f(u16 u) {
    union { unsigned int i; float f; } v;
    v.i = ((unsigned int)u) << 16;
    return v.f;
}
// fp32 -> bf16 round-to-nearest-even
__device__ __forceinline__ u16 f2bf(float f) {
    union { float f; unsigned int u; } v;
    v.f = f;
    unsigned int r = (v.u + 0x7FFFu + ((v.u >> 16) & 1u)) >> 16;
    return (u16)r;
}

struct f8 { float v[8]; };

// load 8 contiguous elements (element index `idx`) as fp32
template<bool BF>
__device__ __forceinline__ f8 loadf8(const void* p, size_t idx) {
    f8 r;
    if constexpr (BF) {
        short8 s = *(const short8*)((const u16*)p + idx);
#pragma unroll
        for (int j = 0; j < 8; ++j) r.v[j] = bf2f((u16)s[j]);
    } else {
        const float* f = (const float*)p + idx;
        floatx4 a = *(const floatx4*)f;
        floatx4 b = *(const floatx4*)(f + 4);
#pragma unroll
        for (int j = 0; j < 4; ++j) { r.v[j] = a[j]; r.v[4 + j] = b[j]; }
    }
    return r;
}

// load 8 contiguous elements as bf16 bits
template<bool BF>
__device__ __forceinline__ short8 load8bf(const void* p, size_t idx) {
    if constexpr (BF) {
        return *(const short8*)((const u16*)p + idx);
    } else {
        const float* f = (const float*)p + idx;
        floatx4 a = *(const floatx4*)f;
        floatx4 b = *(const floatx4*)(f + 4);
        short8 s;
#pragma unroll
        for (int j = 0; j < 4; ++j) { s[j] = (short)f2bf(a[j]); s[4 + j] = (short)f2bf(b[j]); }
        return s;
    }
}

// ---------------------------------------------------------------------------
// Dtype detector: flag = 1 => bf16 data, 0 => fp32 data.
// ---------------------------------------------------------------------------
__global__ void detect_kernel(const u16* __restrict__ x16, int* __restrict__ flag) {
    __shared__ int cnt;
    if (threadIdx.x == 0) cnt = 0;
    __syncthreads();
    int local = 0;
#pragma unroll
    for (int i = 0; i < 32; ++i) {
        u16 u = x16[(size_t)(threadIdx.x * 32 + i) * 2];
        int e = (u >> 7) & 0xFF;
        local += (e < 100 || e > 150) ? 1 : 0;
    }
    atomicAdd(&cnt, local);
    __syncthreads();
    if (threadIdx.x == 0) *flag = (cnt < 2048) ? 1 : 0;
}

// ---------------------------------------------------------------------------
// fp32 -> bf16 stream conversion (for W / lora_A), flag-gated.
// ---------------------------------------------------------------------------
__global__ __launch_bounds__(256) void cvt_kernel(
    const float* __restrict__ src, u16* __restrict__ dst, int n8,
    const int* __restrict__ flag, int want)
{
    if (*flag != want) return;
    int idx = blockIdx.x * 256 + threadIdx.x;
    if (idx >= n8) return;
    short8 s = load8bf<false>(src, (size_t)idx * 8);
    *(short8*)(dst + (size_t)idx * 8) = s;
}

// ---------------------------------------------------------------------------
// Router: one wave per token. Also (fp32 path) emits x in bf16 to xb -- this
// fuses the x-conversion pass into a kernel that already streams all of x.
// ---------------------------------------------------------------------------
template<bool BF>
__global__ __launch_bounds__(256) void routing_kernel(
    const void* __restrict__ x, const void* __restrict__ gate_w,
    float* __restrict__ s_te, u16* __restrict__ xb,
    const int* __restrict__ flag, int want)
{
    if (*flag != want) return;
    int lane = threadIdx.x & 63;
    int wave = threadIdx.x >> 6;
    int t = blockIdx.x * 4 + wave;

    float acc[E_NUM];
#pragma unroll
    for (int e = 0; e < E_NUM; ++e) acc[e] = 0.f;

#pragma unroll
    for (int i = 0; i < 6; ++i) {               // 6 * 64 lanes * 8 = 3072
        size_t d = (size_t)(i * 64 + lane) * 8;
        f8 xv = loadf8<BF>(x, (size_t)t * D_DIM + d);
        if constexpr (!BF) {
            if (xb) {
                short8 s;
#pragma unroll
                for (int j = 0; j < 8; ++j) s[j] = (short)f2bf(xv.v[j]);
                *(short8*)(xb + (size_t)t * D_DIM + d) = s;
            }
        }
#pragma unroll
        for (int e = 0; e < E_NUM; ++e) {
            f8 gv = loadf8<BF>(gate_w, (size_t)e * D_DIM + d);
#pragma unroll
            for (int j = 0; j < 8; ++j) acc[e] += xv.v[j] * gv.v[j];
        }
    }
#pragma unroll
    for (int e = 0; e < E_NUM; ++e) {
#pragma unroll
        for (int off = 32; off > 0; off >>= 1)
            acc[e] += __shfl_xor(acc[e], off, 64);
    }
    if (lane == 0) {
        int i0 = 0; float l0 = acc[0];
        for (int e = 1; e < E_NUM; ++e) if (acc[e] > l0) { l0 = acc[e]; i0 = e; }
        int i1 = -1; float l1 = -1e30f;
        for (int e = 0; e < E_NUM; ++e) if (e != i0 && acc[e] > l1) { l1 = acc[e]; i1 = e; }
        float w0 = 1.f / (1.f + __expf(l1 - l0));   // renormalized top-2 softmax
        float w1 = 1.f - w0;
        float s[E_NUM];
#pragma unroll
        for (int e = 0; e < E_NUM; ++e) s[e] = 0.f;
        s[i0] = 2.f * w0;
        s[i1] = 2.f * w1;
#pragma unroll
        for (int e = 0; e < E_NUM; ++e) s_te[(size_t)t * E_NUM + e] = s[e];
    }
}

// ---------------------------------------------------------------------------
// Pack lora_B [E,O,R] -> B_pack [O, E*R] (bf16, K-major like W).
// ---------------------------------------------------------------------------
template<bool BF>
__global__ __launch_bounds__(256) void pack_b_kernel(
    const void* __restrict__ loraB, u16* __restrict__ Bp,
    const int* __restrict__ flag, int want)
{
    if (*flag != want) return;
    int idx = blockIdx.x * 256 + threadIdx.x;     // idx = e*O + o
    int e = idx / O_DIM;
    int o = idx - e * O_DIM;
#pragma unroll
    for (int i = 0; i < 4; ++i) {
        short8 s = load8bf<BF>(loraB, (size_t)idx * R_DIM + i * 8);
        *(short8*)(Bp + (size_t)o * KA + e * R_DIM + i * 8) = s;
    }
}

// ---------------------------------------------------------------------------
// 128x128 MFMA GEMM, BK=64, 4 waves of 64x64, dual K-source.
// This version: XOR-swizzled LDS (kills the 16-way ds_read_b128 bank
// conflict of the row-major [128][64] layout), double-buffered LDS with
// register prefetch of the next K-tile (one barrier per tile), so global
// latency hides under the MFMA phase.
// LDS element offset: row*64 + (col ^ ((row&7)*8)) -- applied identically
// on ds_write (staging) and ds_read (fragments); col is always a multiple
// of 8 elements (16 B), so the XOR permutes 16B slots within the row.
// ---------------------------------------------------------------------------
template<bool BF1, bool OUTBF>
__global__ __launch_bounds__(256) void gemm_kernel(
    const void* __restrict__ A1, int lda1, int kt1,
    const u16* __restrict__ A2, int lda2, int kt2,
    const void* __restrict__ B1, int ldb1,
    const u16* __restrict__ B2, int ldb2,
    void* __restrict__ outv, int ldo,
    const float* __restrict__ s_te, int scale_mode,
    const int* __restrict__ flag, int want)
{
    if (*flag != want) return;
    __shared__ short As[2][128 * 64];
    __shared__ short Bs[2][128 * 64];

    const int tid  = threadIdx.x;
    const int lane = tid & 63;
    const int wave = tid >> 6;
    const int rowA0 = blockIdx.x * 128;
    const int rowB0 = blockIdx.y * 128;

    floatx4 acc[4][4];
#pragma unroll
    for (int mi = 0; mi < 4; ++mi)
#pragma unroll
        for (int ni = 0; ni < 4; ++ni)
            acc[mi][ni] = (floatx4){0.f, 0.f, 0.f, 0.f};

    const int m_base = (wave & 1) * 64;
    const int n_base = (wave >> 1) * 64;
    const int quad = lane >> 4;
    const int r16  = lane & 15;

    // staging geometry: per thread 4 chunks of 8 elems for each of A and B.
    int srow[4], scol[4], soff[4];
#pragma unroll
    for (int i = 0; i < 4; ++i) {
        int c = wave * 256 + i * 64 + lane;
        int r = c >> 3, c8 = c & 7;
        srow[i] = r;
        scol[i] = c8 * 8;
        soff[i] = r * 64 + ((c8 ^ (r & 7)) * 8);   // swizzled LDS elem offset
    }

    auto LD = [&](int kt, short8 av[4], short8 bv[4]) {
        if (kt < kt1) {
            const int ko = kt * 64;
#pragma unroll
            for (int i = 0; i < 4; ++i) {
                av[i] = load8bf<BF1>(A1, (size_t)(rowA0 + srow[i]) * lda1 + ko + scol[i]);
                bv[i] = load8bf<BF1>(B1, (size_t)(rowB0 + srow[i]) * ldb1 + ko + scol[i]);
            }
        } else {
            const int ko = (kt - kt1) * 64;
#pragma unroll
            for (int i = 0; i < 4; ++i) {
                av[i] = *(const short8*)(A2 + (size_t)(rowA0 + srow[i]) * lda2 + ko + scol[i]);
                bv[i] = *(const short8*)(B2 + (size_t)(rowB0 + srow[i]) * ldb2 + ko + scol[i]);
            }
        }
    };
    auto ST = [&](int buf, const short8 av[4], const short8 bv[4]) {
#pragma unroll
        for (int i = 0; i < 4; ++i) {
            *(short8*)(&As[buf][soff[i]]) = av[i];
            *(short8*)(&Bs[buf][soff[i]]) = bv[i];
        }
    };

    const int ktot = kt1 + kt2;
    short8 pa[4], pb[4];
    LD(0, pa, pb);
    ST(0, pa, pb);
    __syncthreads();
    int cur = 0;

    for (int kt = 0; kt < ktot; ++kt) {
        const bool more = (kt + 1 < ktot);
        if (more) LD(kt + 1, pa, pb);           // issue next-tile loads early

#pragma unroll
        for (int kk = 0; kk < 64; kk += 32) {
            short8 af[4], bfg[4];
#pragma unroll
            for (int mi = 0; mi < 4; ++mi) {
                const int row = m_base + mi * 16 + r16;
                af[mi] = *(const short8*)(&As[cur][row * 64 + ((kk + quad * 8) ^ ((row & 7) * 8))]);
            }
#pragma unroll
            for (int ni = 0; ni < 4; ++ni) {
                const int row = n_base + ni * 16 + r16;
                bfg[ni] = *(const short8*)(&Bs[cur][row * 64 + ((kk + quad * 8) ^ ((row & 7) * 8))]);
            }
#pragma unroll
            for (int mi = 0; mi < 4; ++mi)
#pragma unroll
                for (int ni = 0; ni < 4; ++ni)
                    acc[mi][ni] = __builtin_amdgcn_mfma_f32_16x16x32_bf16(
                        af[mi], bfg[ni], acc[mi][ni], 0, 0, 0);
        }

        if (more) {
            ST(cur ^ 1, pa, pb);                // write other buffer; no race:
            __syncthreads();                    // one barrier per K-tile
            cur ^= 1;
        }
    }

    // Epilogue. C/D layout (m89-verified): col n = lane&15, row m = quad*4+reg.
#pragma unroll
    for (int mi = 0; mi < 4; ++mi) {
#pragma unroll
        for (int r = 0; r < 4; ++r) {
            int t = rowA0 + m_base + mi * 16 + quad * 4 + r;
#pragma unroll
            for (int ni = 0; ni < 4; ++ni) {
                int o = rowB0 + n_base + ni * 16 + r16;
                float v = acc[mi][ni][r];
                if (scale_mode) v *= s_te[(size_t)t * E_NUM + (o >> 5)];
                if constexpr (OUTBF)
                    ((u16*)outv)[(size_t)t * ldo + o] = f2bf(v);
                else
                    ((float*)outv)[(size_t)t * ldo + o] = v;
            }
        }
    }
}

// ---------------------------------------------------------------------------
extern "C" void kernel_launch(void* const* d_in, const int* in_sizes, int n_in,
                              void* d_out, int out_size, void* d_ws, size_t ws_size,
                              hipStream_t stream)
{
    const void* x      = d_in[0];   // [T, D]
    const void* W      = d_in[1];   // [O, D]
    const void* gate_w = d_in[2];   // [E, D]
    const void* lora_A = d_in[3];   // [E*R, D]
    const void* lora_B = d_in[4];   // [E, O, R]

    // workspace layout
    int*   flag     = (int*)d_ws;
    float* s_te     = (float*)((char*)d_ws + 1024);
    u16*   a_scaled = (u16*)((char*)d_ws + 1024 + 524288);                 // [T, 256] bf16
    u16*   B_pack   = (u16*)((char*)d_ws + 1024 + 524288 + 8388608);       // [O, 256] bf16
    const size_t base_sz = 1024 + 524288 + 8388608 + 1572864;

    // optional bf16 mirrors of the fp32 inputs (big-workspace fast path)
    const size_t x16_sz = (size_t)T_NUM * D_DIM * 2;   // 100.7 MB
    const size_t W16_sz = (size_t)O_DIM * D_DIM * 2;   //  18.9 MB
    const size_t A16_sz = (size_t)KA * D_DIM * 2;      //   1.6 MB
    const bool big = ws_size >= base_sz + x16_sz + W16_sz + A16_sz;
    u16* x16 = big ? (u16*)((char*)d_ws + base_sz) : nullptr;
    u16* W16 = big ? (u16*)((char*)x16 + x16_sz)   : nullptr;
    u16* A16 = big ? (u16*)((char*)W16 + W16_sz)   : nullptr;

    detect_kernel<<<1, 256, 0, stream>>>((const u16*)x, flag);

    // routing (fp32 variant also streams x out as bf16 when workspace allows)
    routing_kernel<true ><<<T_NUM / 4, 256, 0, stream>>>(x, gate_w, s_te, nullptr, flag, 1);
    routing_kernel<false><<<T_NUM / 4, 256, 0, stream>>>(x, gate_w, s_te, x16, flag, 0);

    pack_b_kernel<true ><<<(E_NUM * O_DIM) / 256, 256, 0, stream>>>(lora_B, B_pack, flag, 1);
    pack_b_kernel<false><<<(E_NUM * O_DIM) / 256, 256, 0, stream>>>(lora_B, B_pack, flag, 0);

    // -------- flag==1 (inputs already bf16): read inputs directly ----------
    gemm_kernel<true, true><<<dim3(T_NUM / 128, KA / 128), 256, 0, stream>>>(
        x, D_DIM, D_DIM / 64, (const u16*)x, D_DIM, 0,
        lora_A, D_DIM, (const u16*)lora_A, D_DIM,
        a_scaled, KA, s_te, 1, flag, 1);
    gemm_kernel<true, true><<<dim3(T_NUM / 128, O_DIM / 128), 256, 0, stream>>>(
        x, D_DIM, D_DIM / 64, a_scaled, KA, KA / 64,
        W, D_DIM, B_pack, KA,
        d_out, O_DIM, nullptr, 0, flag, 1);

    // -------- flag==0 (fp32 inputs) ----------------------------------------
    if (big) {
        // convert W and lora_A once; x was converted inside routing_kernel
        cvt_kernel<<<(O_DIM * D_DIM / 8 + 255) / 256, 256, 0, stream>>>(
            (const float*)W, W16, O_DIM * D_DIM / 8, flag, 0);
        cvt_kernel<<<(KA * D_DIM / 8 + 255) / 256, 256, 0, stream>>>(
            (const float*)lora_A, A16, KA * D_DIM / 8, flag, 0);

        gemm_kernel<true, true><<<dim3(T_NUM / 128, KA / 128), 256, 0, stream>>>(
            x16, D_DIM, D_DIM / 64, x16, D_DIM, 0,
            A16, D_DIM, A16, D_DIM,
            a_scaled, KA, s_te, 1, flag, 0);
        gemm_kernel<true, false><<<dim3(T_NUM / 128, O_DIM / 128), 256, 0, stream>>>(
            x16, D_DIM, D_DIM / 64, a_scaled, KA, KA / 64,
            W16, D_DIM, B_pack, KA,
            d_out, O_DIM, nullptr, 0, flag, 0);
    } else {
        // fallback: stage fp32 directly (cvt in staging path)
        gemm_kernel<false, true><<<dim3(T_NUM / 128, KA / 128), 256, 0, stream>>>(
            x, D_DIM, D_DIM / 64, (const u16*)x, D_DIM, 0,
            lora_A, D_DIM, (const u16*)lora_A, D_DIM,
            a_scaled, KA, s_te, 1, flag, 0);
        gemm_kernel<false, false><<<dim3(T_NUM / 128, O_DIM / 128), 256, 0, stream>>>(
            x, D_DIM, D_DIM / 64, a_scaled, KA, KA / 64,
            W, D_DIM, B_pack, KA,
            d_out, O_DIM, nullptr, 0, flag, 0);
    }
}

// Round 2
// 830.993 us; speedup vs baseline: 1.9139x; 1.0381x over previous
//
#include <hip/hip_runtime.h>
#include <hip/hip_bf16.h>
#include <stdint.h>

typedef unsigned short u16;
typedef __attribute__((ext_vector_type(8))) short short8;
typedef __attribute__((ext_vector_type(4))) float floatx4;

#define T_NUM 16384
#define D_DIM 3072
#define O_DIM 3072
#define E_NUM 8
#define R_DIM 32
#define KA    (E_NUM * R_DIM)   // 256 augmented-K columns

__device__ __forceinline__ float bf2f(u16 u) {
    union { unsigned int i; float f; } v;
    v.i = ((unsigned int)u) << 16;
    return v.f;
}
// fp32 -> bf16 round-to-nearest-even
__device__ __forceinline__ u16 f2bf(float f) {
    union { float f; unsigned int u; } v;
    v.f = f;
    unsigned int r = (v.u + 0x7FFFu + ((v.u >> 16) & 1u)) >> 16;
    return (u16)r;
}

struct f8 { float v[8]; };

template<bool BF>
__device__ __forceinline__ f8 loadf8(const void* p, size_t idx) {
    f8 r;
    if constexpr (BF) {
        short8 s = *(const short8*)((const u16*)p + idx);
#pragma unroll
        for (int j = 0; j < 8; ++j) r.v[j] = bf2f((u16)s[j]);
    } else {
        const float* f = (const float*)p + idx;
        floatx4 a = *(const floatx4*)f;
        floatx4 b = *(const floatx4*)(f + 4);
#pragma unroll
        for (int j = 0; j < 4; ++j) { r.v[j] = a[j]; r.v[4 + j] = b[j]; }
    }
    return r;
}

template<bool BF>
__device__ __forceinline__ short8 load8bf(const void* p, size_t idx) {
    if constexpr (BF) {
        return *(const short8*)((const u16*)p + idx);
    } else {
        const float* f = (const float*)p + idx;
        floatx4 a = *(const floatx4*)f;
        floatx4 b = *(const floatx4*)(f + 4);
        short8 s;
#pragma unroll
        for (int j = 0; j < 4; ++j) { s[j] = (short)f2bf(a[j]); s[4 + j] = (short)f2bf(b[j]); }
        return s;
    }
}

// async global -> LDS, 16B per lane, linear dest (wave-uniform base + lane*16)
__device__ __forceinline__ void gload16(const u16* g, const short* l) {
    __builtin_amdgcn_global_load_lds(
        (const __attribute__((address_space(1))) void*)g,
        (__attribute__((address_space(3))) void*)l, 16, 0, 0);
}

#define BARR  asm volatile("s_barrier" ::: "memory")
#define LGKM0 asm volatile("s_waitcnt lgkmcnt(0)" ::: "memory")

// ---------------------------------------------------------------------------
// Dtype detector: flag = 1 => bf16 data, 0 => fp32 data.
// ---------------------------------------------------------------------------
__global__ void detect_kernel(const u16* __restrict__ x16, int* __restrict__ flag) {
    __shared__ int cnt;
    if (threadIdx.x == 0) cnt = 0;
    __syncthreads();
    int local = 0;
#pragma unroll
    for (int i = 0; i < 32; ++i) {
        u16 u = x16[(size_t)(threadIdx.x * 32 + i) * 2];
        int e = (u >> 7) & 0xFF;
        local += (e < 100 || e > 150) ? 1 : 0;
    }
    atomicAdd(&cnt, local);
    __syncthreads();
    if (threadIdx.x == 0) *flag = (cnt < 2048) ? 1 : 0;
}

// ---------------------------------------------------------------------------
// fp32 -> bf16 stream conversion (for W / lora_A), flag-gated.
// ---------------------------------------------------------------------------
__global__ __launch_bounds__(256) void cvt_kernel(
    const float* __restrict__ src, u16* __restrict__ dst, int n8,
    const int* __restrict__ flag, int want)
{
    if (*flag != want) return;
    int idx = blockIdx.x * 256 + threadIdx.x;
    if (idx >= n8) return;
    short8 s = load8bf<false>(src, (size_t)idx * 8);
    *(short8*)(dst + (size_t)idx * 8) = s;
}

// ---------------------------------------------------------------------------
// Router: one wave per token; fp32 path also emits x as bf16.
// ---------------------------------------------------------------------------
template<bool BF>
__global__ __launch_bounds__(256) void routing_kernel(
    const void* __restrict__ x, const void* __restrict__ gate_w,
    float* __restrict__ s_te, u16* __restrict__ xb,
    const int* __restrict__ flag, int want)
{
    if (*flag != want) return;
    int lane = threadIdx.x & 63;
    int wave = threadIdx.x >> 6;
    int t = blockIdx.x * 4 + wave;

    float acc[E_NUM];
#pragma unroll
    for (int e = 0; e < E_NUM; ++e) acc[e] = 0.f;

#pragma unroll
    for (int i = 0; i < 6; ++i) {               // 6 * 64 lanes * 8 = 3072
        size_t d = (size_t)(i * 64 + lane) * 8;
        f8 xv = loadf8<BF>(x, (size_t)t * D_DIM + d);
        if constexpr (!BF) {
            if (xb) {
                short8 s;
#pragma unroll
                for (int j = 0; j < 8; ++j) s[j] = (short)f2bf(xv.v[j]);
                *(short8*)(xb + (size_t)t * D_DIM + d) = s;
            }
        }
#pragma unroll
        for (int e = 0; e < E_NUM; ++e) {
            f8 gv = loadf8<BF>(gate_w, (size_t)e * D_DIM + d);
#pragma unroll
            for (int j = 0; j < 8; ++j) acc[e] += xv.v[j] * gv.v[j];
        }
    }
#pragma unroll
    for (int e = 0; e < E_NUM; ++e) {
#pragma unroll
        for (int off = 32; off > 0; off >>= 1)
            acc[e] += __shfl_xor(acc[e], off, 64);
    }
    if (lane == 0) {
        int i0 = 0; float l0 = acc[0];
        for (int e = 1; e < E_NUM; ++e) if (acc[e] > l0) { l0 = acc[e]; i0 = e; }
        int i1 = -1; float l1 = -1e30f;
        for (int e = 0; e < E_NUM; ++e) if (e != i0 && acc[e] > l1) { l1 = acc[e]; i1 = e; }
        float w0 = 1.f / (1.f + __expf(l1 - l0));
        float w1 = 1.f - w0;
        float s[E_NUM];
#pragma unroll
        for (int e = 0; e < E_NUM; ++e) s[e] = 0.f;
        s[i0] = 2.f * w0;
        s[i1] = 2.f * w1;
#pragma unroll
        for (int e = 0; e < E_NUM; ++e) s_te[(size_t)t * E_NUM + e] = s[e];
    }
}

// ---------------------------------------------------------------------------
// Pack lora_B [E,O,R] -> B_pack [O, E*R] (bf16, K-major like W).
// ---------------------------------------------------------------------------
template<bool BF>
__global__ __launch_bounds__(256) void pack_b_kernel(
    const void* __restrict__ loraB, u16* __restrict__ Bp,
    const int* __restrict__ flag, int want)
{
    if (*flag != want) return;
    int idx = blockIdx.x * 256 + threadIdx.x;     // idx = e*O + o
    int e = idx / O_DIM;
    int o = idx - e * O_DIM;
#pragma unroll
    for (int i = 0; i < 4; ++i) {
        short8 s = load8bf<BF>(loraB, (size_t)idx * R_DIM + i * 8);
        *(short8*)(Bp + (size_t)o * KA + e * R_DIM + i * 8) = s;
    }
}

// ---------------------------------------------------------------------------
// 128x128 MFMA GEMM (round-1 verified): used for GEMM1 and fp32 fallbacks.
// ---------------------------------------------------------------------------
template<bool BF1, bool OUTBF>
__global__ __launch_bounds__(256) void gemm_kernel(
    const void* __restrict__ A1, int lda1, int kt1,
    const u16* __restrict__ A2, int lda2, int kt2,
    const void* __restrict__ B1, int ldb1,
    const u16* __restrict__ B2, int ldb2,
    void* __restrict__ outv, int ldo,
    const float* __restrict__ s_te, int scale_mode,
    const int* __restrict__ flag, int want)
{
    if (*flag != want) return;
    __shared__ short As[2][128 * 64];
    __shared__ short Bs[2][128 * 64];

    const int tid  = threadIdx.x;
    const int lane = tid & 63;
    const int wave = tid >> 6;
    const int rowA0 = blockIdx.x * 128;
    const int rowB0 = blockIdx.y * 128;

    floatx4 acc[4][4];
#pragma unroll
    for (int mi = 0; mi < 4; ++mi)
#pragma unroll
        for (int ni = 0; ni < 4; ++ni)
            acc[mi][ni] = (floatx4){0.f, 0.f, 0.f, 0.f};

    const int m_base = (wave & 1) * 64;
    const int n_base = (wave >> 1) * 64;
    const int quad = lane >> 4;
    const int r16  = lane & 15;

    int srow[4], scol[4], soff[4];
#pragma unroll
    for (int i = 0; i < 4; ++i) {
        int c = wave * 256 + i * 64 + lane;
        int r = c >> 3, c8 = c & 7;
        srow[i] = r;
        scol[i] = c8 * 8;
        soff[i] = r * 64 + ((c8 ^ (r & 7)) * 8);
    }

    auto LD = [&](int kt, short8 av[4], short8 bv[4]) {
        if (kt < kt1) {
            const int ko = kt * 64;
#pragma unroll
            for (int i = 0; i < 4; ++i) {
                av[i] = load8bf<BF1>(A1, (size_t)(rowA0 + srow[i]) * lda1 + ko + scol[i]);
                bv[i] = load8bf<BF1>(B1, (size_t)(rowB0 + srow[i]) * ldb1 + ko + scol[i]);
            }
        } else {
            const int ko = (kt - kt1) * 64;
#pragma unroll
            for (int i = 0; i < 4; ++i) {
                av[i] = *(const short8*)(A2 + (size_t)(rowA0 + srow[i]) * lda2 + ko + scol[i]);
                bv[i] = *(const short8*)(B2 + (size_t)(rowB0 + srow[i]) * ldb2 + ko + scol[i]);
            }
        }
    };
    auto ST = [&](int buf, const short8 av[4], const short8 bv[4]) {
#pragma unroll
        for (int i = 0; i < 4; ++i) {
            *(short8*)(&As[buf][soff[i]]) = av[i];
            *(short8*)(&Bs[buf][soff[i]]) = bv[i];
        }
    };

    const int ktot = kt1 + kt2;
    short8 pa[4], pb[4];
    LD(0, pa, pb);
    ST(0, pa, pb);
    __syncthreads();
    int cur = 0;

    for (int kt = 0; kt < ktot; ++kt) {
        const bool more = (kt + 1 < ktot);
        if (more) LD(kt + 1, pa, pb);

#pragma unroll
        for (int kk = 0; kk < 64; kk += 32) {
            short8 af[4], bfg[4];
#pragma unroll
            for (int mi = 0; mi < 4; ++mi) {
                const int row = m_base + mi * 16 + r16;
                af[mi] = *(const short8*)(&As[cur][row * 64 + ((kk + quad * 8) ^ ((row & 7) * 8))]);
            }
#pragma unroll
            for (int ni = 0; ni < 4; ++ni) {
                const int row = n_base + ni * 16 + r16;
                bfg[ni] = *(const short8*)(&Bs[cur][row * 64 + ((kk + quad * 8) ^ ((row & 7) * 8))]);
            }
#pragma unroll
            for (int mi = 0; mi < 4; ++mi)
#pragma unroll
                for (int ni = 0; ni < 4; ++ni)
                    acc[mi][ni] = __builtin_amdgcn_mfma_f32_16x16x32_bf16(
                        af[mi], bfg[ni], acc[mi][ni], 0, 0, 0);
        }

        if (more) {
            ST(cur ^ 1, pa, pb);
            __syncthreads();
            cur ^= 1;
        }
    }

#pragma unroll
    for (int mi = 0; mi < 4; ++mi) {
#pragma unroll
        for (int r = 0; r < 4; ++r) {
            int t = rowA0 + m_base + mi * 16 + quad * 4 + r;
#pragma unroll
            for (int ni = 0; ni < 4; ++ni) {
                int o = rowB0 + n_base + ni * 16 + r16;
                float v = acc[mi][ni][r];
                if (scale_mode) v *= s_te[(size_t)t * E_NUM + (o >> 5)];
                if constexpr (OUTBF)
                    ((u16*)outv)[(size_t)t * ldo + o] = f2bf(v);
                else
                    ((float*)outv)[(size_t)t * ldo + o] = v;
            }
        }
    }
}

// ---------------------------------------------------------------------------
// 256x256 8-wave MFMA GEMM, BK=64, 4-phase K-tile schedule with counted
// vmcnt (T2+T3+T4+T5 from the verified m201 template), bf16 sources only.
//
// LDS (dynamic, 128 KiB): [A0|A1|B0|B1] x 32 KiB. Staged via
// global_load_lds width=16 with PRE-SWIZZLED per-lane global source:
// DMA writes slot (row, chunk c) <- global chunk (c ^ (row&7)); reads use
// chunk' = g ^ (row&7) -- the exact swizzle that measured 0 conflicts in R1.
//
// Staging of tile kt+1 during tile kt (2/4/2/0 gload_lds per wave in
// phases 0..3; B regions first, A regions ordered by consumption):
//   p0: B q{w,8+w}        p1: B q{16+w,24+w}, A q{w,16+w}; vmcnt(6)
//   p2: A q{8+w,24+w}     p3: vmcnt(2)
// Ledger (per wave, steady state): at p1, outstanding = prev.p2(2)+p0(2)
// +p1(4) = 8 -> vmcnt(6) confirms prev tile's late-A (needed at p2).
// At p3, outstanding = 8 -> vmcnt(2) confirms B+early-A (needed at next
// tile's p0). Last tile: p1 uses vmcnt(0) (nothing else will confirm it).
// Consumption map: wave wm reads A rows wm*128+[32p,32p+32) in phase p
// (regions 0/1 for wm0 at p0-1/p2-3; regions 2/3 for wm1), B region wn
// read only in p0 -- every read is covered by a confirm + barrier.
// ---------------------------------------------------------------------------
template<bool OUTBF>
__global__ __launch_bounds__(512, 2) void gemm256_kernel(
    const u16* __restrict__ A1, int lda1, int kt1,
    const u16* __restrict__ A2, int lda2, int kt2,
    const u16* __restrict__ B1, int ldb1,
    const u16* __restrict__ B2, int ldb2,
    void* __restrict__ outv, int ldo,
    const int* __restrict__ flag, int want)
{
    if (*flag != want) return;
    extern __shared__ short smem[];   // [4][16384]: A0 A1 B0 B1

    const int tid  = threadIdx.x;
    const int lane = tid & 63;
    const int wave = tid >> 6;        // 0..7
    const int wm   = wave >> 2;       // 0..1
    const int wn   = wave & 3;        // 0..3
    const int quad = lane >> 4;
    const int r16  = lane & 15;
    const int rb   = lane >> 3;       // DMA: row-in-8
    const int swz  = (lane & 7) ^ rb; // DMA: pre-swizzled source chunk

    // XCD-chunked bijective block swizzle (grid 64x12 = 768, 768%8==0)
    const int lin = blockIdx.y * 64 + blockIdx.x;
    const int sw  = (lin & 7) * 96 + (lin >> 3);
    const int rowA0 = (sw & 63) * 256;
    const int rowB0 = (sw >> 6) * 256;

    floatx4 acc[8][4];
#pragma unroll
    for (int mi = 0; mi < 8; ++mi)
#pragma unroll
        for (int ni = 0; ni < 4; ++ni)
            acc[mi][ni] = (floatx4){0.f, 0.f, 0.f, 0.f};

    const int ktot = kt1 + kt2;

    // stage instruction q (rows 8q..8q+7) of tile ks into buffer nb
    auto stA = [&](int nb, int q, int ks) {
        const u16* g;
        if (ks < kt1) g = A1 + (size_t)(rowA0 + q * 8 + rb) * lda1 + (size_t)ks * 64 + swz * 8;
        else          g = A2 + (size_t)(rowA0 + q * 8 + rb) * lda2 + (size_t)(ks - kt1) * 64 + swz * 8;
        gload16(g, smem + nb * 16384 + q * 512);
    };
    auto stB = [&](int nb, int q, int ks) {
        const u16* g;
        if (ks < kt1) g = B1 + (size_t)(rowB0 + q * 8 + rb) * ldb1 + (size_t)ks * 64 + swz * 8;
        else          g = B2 + (size_t)(rowB0 + q * 8 + rb) * ldb2 + (size_t)(ks - kt1) * 64 + swz * 8;
        gload16(g, smem + 32768 + nb * 16384 + q * 512);
    };

    // prologue: fully stage tile 0 into buffer 0
    stB(0, wave, 0); stB(0, 8 + wave, 0); stB(0, 16 + wave, 0); stB(0, 24 + wave, 0);
    stA(0, wave, 0); stA(0, 8 + wave, 0); stA(0, 16 + wave, 0); stA(0, 24 + wave, 0);
    asm volatile("s_waitcnt vmcnt(0)" ::: "memory");
    BARR;

    int cur = 0;
    short8 bf[4][2];

    for (int kt = 0; kt < ktot; ++kt) {
        const int  ks   = kt + 1;
        const bool more = ks < ktot;
        const int  nb   = cur ^ 1;
        const short* Acur = smem + cur * 16384;
        const short* Bcur = smem + 32768 + cur * 16384;

        auto rdA = [&](int p, short8 af[2][2]) {
#pragma unroll
            for (int m2 = 0; m2 < 2; ++m2) {
                const int rowm = wm * 128 + (2 * p + m2) * 16 + r16;
                const int sx = rowm & 7;
#pragma unroll
                for (int kx = 0; kx < 2; ++kx)
                    af[m2][kx] = *(const short8*)(Acur + rowm * 64 + (((quad + 4 * kx) ^ sx) * 8));
            }
        };
        auto domfma = [&](int p, short8 af[2][2]) {
#pragma unroll
            for (int m2 = 0; m2 < 2; ++m2)
#pragma unroll
                for (int kx = 0; kx < 2; ++kx)
#pragma unroll
                    for (int ni = 0; ni < 4; ++ni)
                        acc[2 * p + m2][ni] = __builtin_amdgcn_mfma_f32_16x16x32_bf16(
                            af[m2][kx], bf[ni][kx], acc[2 * p + m2][ni], 0, 0, 0);
        };

        short8 af[2][2];

        // ---- phase 0: read A rows [0,32)+wm*128, all B frags; stage B0,B1
        rdA(0, af);
#pragma unroll
        for (int ni = 0; ni < 4; ++ni) {
            const int rown = wn * 64 + ni * 16 + r16;
            const int sx = rown & 7;
#pragma unroll
            for (int kx = 0; kx < 2; ++kx)
                bf[ni][kx] = *(const short8*)(Bcur + rown * 64 + (((quad + 4 * kx) ^ sx) * 8));
        }
        if (more) { stB(nb, wave, ks); stB(nb, 8 + wave, ks); }
        BARR; LGKM0;
        __builtin_amdgcn_s_setprio(1);
        domfma(0, af);
        __builtin_amdgcn_s_setprio(0);
        BARR;

        // ---- phase 1: stage B2,B3 + A0,A2; confirm prev tile's late A
        rdA(1, af);
        if (more) {
            stB(nb, 16 + wave, ks); stB(nb, 24 + wave, ks);
            stA(nb, wave, ks);      stA(nb, 16 + wave, ks);
            asm volatile("s_waitcnt vmcnt(6)" ::: "memory");
        } else {
            asm volatile("s_waitcnt vmcnt(0)" ::: "memory");
        }
        BARR; LGKM0;
        __builtin_amdgcn_s_setprio(1);
        domfma(1, af);
        __builtin_amdgcn_s_setprio(0);
        BARR;

        // ---- phase 2: stage A1,A3
        rdA(2, af);
        if (more) { stA(nb, 8 + wave, ks); stA(nb, 24 + wave, ks); }
        BARR; LGKM0;
        __builtin_amdgcn_s_setprio(1);
        domfma(2, af);
        __builtin_amdgcn_s_setprio(0);
        BARR;

        // ---- phase 3: confirm B + early-A of next tile
        rdA(3, af);
        if (more) asm volatile("s_waitcnt vmcnt(2)" ::: "memory");
        BARR; LGKM0;
        __builtin_amdgcn_s_setprio(1);
        domfma(3, af);
        __builtin_amdgcn_s_setprio(0);
        BARR;

        cur = nb;
    }

    // epilogue: C/D layout col = lane&15, row = quad*4+reg
#pragma unroll
    for (int mi = 0; mi < 8; ++mi) {
#pragma unroll
        for (int r = 0; r < 4; ++r) {
            const int t = rowA0 + wm * 128 + mi * 16 + quad * 4 + r;
#pragma unroll
            for (int ni = 0; ni < 4; ++ni) {
                const int o = rowB0 + wn * 64 + ni * 16 + r16;
                float v = acc[mi][ni][r];
                if constexpr (OUTBF)
                    ((u16*)outv)[(size_t)t * ldo + o] = f2bf(v);
                else
                    ((float*)outv)[(size_t)t * ldo + o] = v;
            }
        }
    }
}

// ---------------------------------------------------------------------------
extern "C" void kernel_launch(void* const* d_in, const int* in_sizes, int n_in,
                              void* d_out, int out_size, void* d_ws, size_t ws_size,
                              hipStream_t stream)
{
    const void* x      = d_in[0];   // [T, D]
    const void* W      = d_in[1];   // [O, D]
    const void* gate_w = d_in[2];   // [E, D]
    const void* lora_A = d_in[3];   // [E*R, D]
    const void* lora_B = d_in[4];   // [E, O, R]

    int*   flag     = (int*)d_ws;
    float* s_te     = (float*)((char*)d_ws + 1024);
    u16*   a_scaled = (u16*)((char*)d_ws + 1024 + 524288);                 // [T, 256] bf16
    u16*   B_pack   = (u16*)((char*)d_ws + 1024 + 524288 + 8388608);       // [O, 256] bf16
    const size_t base_sz = 1024 + 524288 + 8388608 + 1572864;

    const size_t x16_sz = (size_t)T_NUM * D_DIM * 2;
    const size_t W16_sz = (size_t)O_DIM * D_DIM * 2;
    const size_t A16_sz = (size_t)KA * D_DIM * 2;
    const bool big = ws_size >= base_sz + x16_sz + W16_sz + A16_sz;
    u16* x16 = big ? (u16*)((char*)d_ws + base_sz) : nullptr;
    u16* W16 = big ? (u16*)((char*)x16 + x16_sz)   : nullptr;
    u16* A16 = big ? (u16*)((char*)W16 + W16_sz)   : nullptr;

    // opt-in to 128 KiB dynamic LDS for the 256^2 kernel (idempotent)
    (void)hipFuncSetAttribute((const void*)gemm256_kernel<true>,
                              hipFuncAttributeMaxDynamicSharedMemorySize, 131072);
    (void)hipFuncSetAttribute((const void*)gemm256_kernel<false>,
                              hipFuncAttributeMaxDynamicSharedMemorySize, 131072);

    detect_kernel<<<1, 256, 0, stream>>>((const u16*)x, flag);

    routing_kernel<true ><<<T_NUM / 4, 256, 0, stream>>>(x, gate_w, s_te, nullptr, flag, 1);
    routing_kernel<false><<<T_NUM / 4, 256, 0, stream>>>(x, gate_w, s_te, x16, flag, 0);

    pack_b_kernel<true ><<<(E_NUM * O_DIM) / 256, 256, 0, stream>>>(lora_B, B_pack, flag, 1);
    pack_b_kernel<false><<<(E_NUM * O_DIM) / 256, 256, 0, stream>>>(lora_B, B_pack, flag, 0);

    const dim3 g2(T_NUM / 256, O_DIM / 256);   // 64 x 12

    // -------- flag==1 (inputs already bf16) --------------------------------
    gemm_kernel<true, true><<<dim3(T_NUM / 128, KA / 128), 256, 0, stream>>>(
        x, D_DIM, D_DIM / 64, (const u16*)x, D_DIM, 0,
        lora_A, D_DIM, (const u16*)lora_A, D_DIM,
        a_scaled, KA, s_te, 1, flag, 1);
    gemm256_kernel<true><<<g2, 512, 131072, stream>>>(
        (const u16*)x, D_DIM, D_DIM / 64, a_scaled, KA, KA / 64,
        (const u16*)W, D_DIM, B_pack, KA,
        d_out, O_DIM, flag, 1);

    // -------- flag==0 (fp32 inputs) ----------------------------------------
    if (big) {
        cvt_kernel<<<(O_DIM * D_DIM / 8 + 255) / 256, 256, 0, stream>>>(
            (const float*)W, W16, O_DIM * D_DIM / 8, flag, 0);
        cvt_kernel<<<(KA * D_DIM / 8 + 255) / 256, 256, 0, stream>>>(
            (const float*)lora_A, A16, KA * D_DIM / 8, flag, 0);

        gemm_kernel<true, true><<<dim3(T_NUM / 128, KA / 128), 256, 0, stream>>>(
            x16, D_DIM, D_DIM / 64, x16, D_DIM, 0,
            A16, D_DIM, A16, D_DIM,
            a_scaled, KA, s_te, 1, flag, 0);
        gemm256_kernel<false><<<g2, 512, 131072, stream>>>(
            x16, D_DIM, D_DIM / 64, a_scaled, KA, KA / 64,
            W16, D_DIM, B_pack, KA,
            d_out, O_DIM, flag, 0);
    } else {
        gemm_kernel<false, true><<<dim3(T_NUM / 128, KA / 128), 256, 0, stream>>>(
            x, D_DIM, D_DIM / 64, (const u16*)x, D_DIM, 0,
            lora_A, D_DIM, (const u16*)lora_A, D_DIM,
            a_scaled, KA, s_te, 1, flag, 0);
        gemm_kernel<false, false><<<dim3(T_NUM / 128, O_DIM / 128), 256, 0, stream>>>(
            x, D_DIM, D_DIM / 64, a_scaled, KA, 4,
            W, D_DIM, B_pack, KA,
            d_out, O_DIM, nullptr, 0, flag, 0);
    }
}

// Round 3
// 804.630 us; speedup vs baseline: 1.9766x; 1.0328x over previous
//
#include <hip/hip_runtime.h>
#include <hip/hip_bf16.h>
#include <stdint.h>

typedef unsigned short u16;
typedef __attribute__((ext_vector_type(8))) short short8;
typedef __attribute__((ext_vector_type(4))) float floatx4;

#define T_NUM 16384
#define D_DIM 3072
#define O_DIM 3072
#define E_NUM 8
#define R_DIM 32
#define KA    (E_NUM * R_DIM)   // 256 augmented-K columns

__device__ __forceinline__ float bf2f(u16 u) {
    union { unsigned int i; float f; } v;
    v.i = ((unsigned int)u) << 16;
    return v.f;
}
// fp32 -> bf16 round-to-nearest-even
__device__ __forceinline__ u16 f2bf(float f) {
    union { float f; unsigned int u; } v;
    v.f = f;
    unsigned int r = (v.u + 0x7FFFu + ((v.u >> 16) & 1u)) >> 16;
    return (u16)r;
}

struct f8 { float v[8]; };

template<bool BF>
__device__ __forceinline__ f8 loadf8(const void* p, size_t idx) {
    f8 r;
    if constexpr (BF) {
        short8 s = *(const short8*)((const u16*)p + idx);
#pragma unroll
        for (int j = 0; j < 8; ++j) r.v[j] = bf2f((u16)s[j]);
    } else {
        const float* f = (const float*)p + idx;
        floatx4 a = *(const floatx4*)f;
        floatx4 b = *(const floatx4*)(f + 4);
#pragma unroll
        for (int j = 0; j < 4; ++j) { r.v[j] = a[j]; r.v[4 + j] = b[j]; }
    }
    return r;
}

template<bool BF>
__device__ __forceinline__ short8 load8bf(const void* p, size_t idx) {
    if constexpr (BF) {
        return *(const short8*)((const u16*)p + idx);
    } else {
        const float* f = (const float*)p + idx;
        floatx4 a = *(const floatx4*)f;
        floatx4 b = *(const floatx4*)(f + 4);
        short8 s;
#pragma unroll
        for (int j = 0; j < 4; ++j) { s[j] = (short)f2bf(a[j]); s[4 + j] = (short)f2bf(b[j]); }
        return s;
    }
}

// async global -> LDS, 16B per lane, linear dest (wave-uniform base + lane*16)
__device__ __forceinline__ void gload16(const u16* g, const short* l) {
    __builtin_amdgcn_global_load_lds(
        (const __attribute__((address_space(1))) void*)g,
        (__attribute__((address_space(3))) void*)l, 16, 0, 0);
}

#define BARR  asm volatile("s_barrier" ::: "memory")
#define LGKM0 asm volatile("s_waitcnt lgkmcnt(0)" ::: "memory")

// ---------------------------------------------------------------------------
// Dtype detector: flag = 1 => bf16 data, 0 => fp32 data. 1024 thr x 8 samples
// (same 8192-sample statistics as before, 4x shorter serial latency chain).
// ---------------------------------------------------------------------------
__global__ void detect_kernel(const u16* __restrict__ x16, int* __restrict__ flag) {
    __shared__ int cnt;
    if (threadIdx.x == 0) cnt = 0;
    __syncthreads();
    int local = 0;
#pragma unroll
    for (int i = 0; i < 8; ++i) {
        u16 u = x16[(size_t)(threadIdx.x * 8 + i) * 2];
        int e = (u >> 7) & 0xFF;
        local += (e < 100 || e > 150) ? 1 : 0;
    }
    atomicAdd(&cnt, local);
    __syncthreads();
    if (threadIdx.x == 0) *flag = (cnt < 2048) ? 1 : 0;
}

// ---------------------------------------------------------------------------
// fp32 -> bf16 stream conversion (for W / lora_A), flag-gated.
// ---------------------------------------------------------------------------
__global__ __launch_bounds__(256) void cvt_kernel(
    const float* __restrict__ src, u16* __restrict__ dst, int n8,
    const int* __restrict__ flag, int want)
{
    if (*flag != want) return;
    int idx = blockIdx.x * 256 + threadIdx.x;
    if (idx >= n8) return;
    short8 s = load8bf<false>(src, (size_t)idx * 8);
    *(short8*)(dst + (size_t)idx * 8) = s;
}

// ---------------------------------------------------------------------------
// Router: one wave per token; fp32 path also emits x as bf16.
// ---------------------------------------------------------------------------
template<bool BF>
__global__ __launch_bounds__(256) void routing_kernel(
    const void* __restrict__ x, const void* __restrict__ gate_w,
    float* __restrict__ s_te, u16* __restrict__ xb,
    const int* __restrict__ flag, int want)
{
    if (*flag != want) return;
    int lane = threadIdx.x & 63;
    int wave = threadIdx.x >> 6;
    int t = blockIdx.x * 4 + wave;

    float acc[E_NUM];
#pragma unroll
    for (int e = 0; e < E_NUM; ++e) acc[e] = 0.f;

#pragma unroll
    for (int i = 0; i < 6; ++i) {               // 6 * 64 lanes * 8 = 3072
        size_t d = (size_t)(i * 64 + lane) * 8;
        f8 xv = loadf8<BF>(x, (size_t)t * D_DIM + d);
        if constexpr (!BF) {
            if (xb) {
                short8 s;
#pragma unroll
                for (int j = 0; j < 8; ++j) s[j] = (short)f2bf(xv.v[j]);
                *(short8*)(xb + (size_t)t * D_DIM + d) = s;
            }
        }
#pragma unroll
        for (int e = 0; e < E_NUM; ++e) {
            f8 gv = loadf8<BF>(gate_w, (size_t)e * D_DIM + d);
#pragma unroll
            for (int j = 0; j < 8; ++j) acc[e] += xv.v[j] * gv.v[j];
        }
    }
#pragma unroll
    for (int e = 0; e < E_NUM; ++e) {
#pragma unroll
        for (int off = 32; off > 0; off >>= 1)
            acc[e] += __shfl_xor(acc[e], off, 64);
    }
    if (lane == 0) {
        int i0 = 0; float l0 = acc[0];
        for (int e = 1; e < E_NUM; ++e) if (acc[e] > l0) { l0 = acc[e]; i0 = e; }
        int i1 = -1; float l1 = -1e30f;
        for (int e = 0; e < E_NUM; ++e) if (e != i0 && acc[e] > l1) { l1 = acc[e]; i1 = e; }
        float w0 = 1.f / (1.f + __expf(l1 - l0));
        float w1 = 1.f - w0;
        float s[E_NUM];
#pragma unroll
        for (int e = 0; e < E_NUM; ++e) s[e] = 0.f;
        s[i0] = 2.f * w0;
        s[i1] = 2.f * w1;
#pragma unroll
        for (int e = 0; e < E_NUM; ++e) s_te[(size_t)t * E_NUM + e] = s[e];
    }
}

// ---------------------------------------------------------------------------
// Pack lora_B [E,O,R] -> B_pack [O, E*R] (bf16, K-major like W).
// ---------------------------------------------------------------------------
template<bool BF>
__global__ __launch_bounds__(256) void pack_b_kernel(
    const void* __restrict__ loraB, u16* __restrict__ Bp,
    const int* __restrict__ flag, int want)
{
    if (*flag != want) return;
    int idx = blockIdx.x * 256 + threadIdx.x;     // idx = e*O + o
    int e = idx / O_DIM;
    int o = idx - e * O_DIM;
#pragma unroll
    for (int i = 0; i < 4; ++i) {
        short8 s = load8bf<BF>(loraB, (size_t)idx * R_DIM + i * 8);
        *(short8*)(Bp + (size_t)o * KA + e * R_DIM + i * 8) = s;
    }
}

// ---------------------------------------------------------------------------
// 128x128 MFMA GEMM (round-1 verified): used for GEMM1 and fp32 fallbacks.
// ---------------------------------------------------------------------------
template<bool BF1, bool OUTBF>
__global__ __launch_bounds__(256) void gemm_kernel(
    const void* __restrict__ A1, int lda1, int kt1,
    const u16* __restrict__ A2, int lda2, int kt2,
    const void* __restrict__ B1, int ldb1,
    const u16* __restrict__ B2, int ldb2,
    void* __restrict__ outv, int ldo,
    const float* __restrict__ s_te, int scale_mode,
    const int* __restrict__ flag, int want)
{
    if (*flag != want) return;
    __shared__ short As[2][128 * 64];
    __shared__ short Bs[2][128 * 64];

    const int tid  = threadIdx.x;
    const int lane = tid & 63;
    const int wave = tid >> 6;
    const int rowA0 = blockIdx.x * 128;
    const int rowB0 = blockIdx.y * 128;

    floatx4 acc[4][4];
#pragma unroll
    for (int mi = 0; mi < 4; ++mi)
#pragma unroll
        for (int ni = 0; ni < 4; ++ni)
            acc[mi][ni] = (floatx4){0.f, 0.f, 0.f, 0.f};

    const int m_base = (wave & 1) * 64;
    const int n_base = (wave >> 1) * 64;
    const int quad = lane >> 4;
    const int r16  = lane & 15;

    int srow[4], scol[4], soff[4];
#pragma unroll
    for (int i = 0; i < 4; ++i) {
        int c = wave * 256 + i * 64 + lane;
        int r = c >> 3, c8 = c & 7;
        srow[i] = r;
        scol[i] = c8 * 8;
        soff[i] = r * 64 + ((c8 ^ (r & 7)) * 8);
    }

    auto LD = [&](int kt, short8 av[4], short8 bv[4]) {
        if (kt < kt1) {
            const int ko = kt * 64;
#pragma unroll
            for (int i = 0; i < 4; ++i) {
                av[i] = load8bf<BF1>(A1, (size_t)(rowA0 + srow[i]) * lda1 + ko + scol[i]);
                bv[i] = load8bf<BF1>(B1, (size_t)(rowB0 + srow[i]) * ldb1 + ko + scol[i]);
            }
        } else {
            const int ko = (kt - kt1) * 64;
#pragma unroll
            for (int i = 0; i < 4; ++i) {
                av[i] = *(const short8*)(A2 + (size_t)(rowA0 + srow[i]) * lda2 + ko + scol[i]);
                bv[i] = *(const short8*)(B2 + (size_t)(rowB0 + srow[i]) * ldb2 + ko + scol[i]);
            }
        }
    };
    auto ST = [&](int buf, const short8 av[4], const short8 bv[4]) {
#pragma unroll
        for (int i = 0; i < 4; ++i) {
            *(short8*)(&As[buf][soff[i]]) = av[i];
            *(short8*)(&Bs[buf][soff[i]]) = bv[i];
        }
    };

    const int ktot = kt1 + kt2;
    short8 pa[4], pb[4];
    LD(0, pa, pb);
    ST(0, pa, pb);
    __syncthreads();
    int cur = 0;

    for (int kt = 0; kt < ktot; ++kt) {
        const bool more = (kt + 1 < ktot);
        if (more) LD(kt + 1, pa, pb);

#pragma unroll
        for (int kk = 0; kk < 64; kk += 32) {
            short8 af[4], bfg[4];
#pragma unroll
            for (int mi = 0; mi < 4; ++mi) {
                const int row = m_base + mi * 16 + r16;
                af[mi] = *(const short8*)(&As[cur][row * 64 + ((kk + quad * 8) ^ ((row & 7) * 8))]);
            }
#pragma unroll
            for (int ni = 0; ni < 4; ++ni) {
                const int row = n_base + ni * 16 + r16;
                bfg[ni] = *(const short8*)(&Bs[cur][row * 64 + ((kk + quad * 8) ^ ((row & 7) * 8))]);
            }
#pragma unroll
            for (int mi = 0; mi < 4; ++mi)
#pragma unroll
                for (int ni = 0; ni < 4; ++ni)
                    acc[mi][ni] = __builtin_amdgcn_mfma_f32_16x16x32_bf16(
                        af[mi], bfg[ni], acc[mi][ni], 0, 0, 0);
        }

        if (more) {
            ST(cur ^ 1, pa, pb);
            __syncthreads();
            cur ^= 1;
        }
    }

#pragma unroll
    for (int mi = 0; mi < 4; ++mi) {
#pragma unroll
        for (int r = 0; r < 4; ++r) {
            int t = rowA0 + m_base + mi * 16 + quad * 4 + r;
#pragma unroll
            for (int ni = 0; ni < 4; ++ni) {
                int o = rowB0 + n_base + ni * 16 + r16;
                float v = acc[mi][ni][r];
                if (scale_mode) v *= s_te[(size_t)t * E_NUM + (o >> 5)];
                if constexpr (OUTBF)
                    ((u16*)outv)[(size_t)t * ldo + o] = f2bf(v);
                else
                    ((float*)outv)[(size_t)t * ldo + o] = v;
            }
        }
    }
}

// ---------------------------------------------------------------------------
// 256x256 8-wave MFMA GEMM, BK=64, 4-phase schedule with counted vmcnt.
// Round-3 changes vs round 2 (same sync structure / ledger, verified R2):
//  * staging: per-lane incremental pointers (+64 elems/tile), single
//    uniform source-switch at kt1 -- no per-load branch, no per-load
//    64-bit address rebuild.
//  * ds_reads: 4 per-tile base pointers (A/B x k-half); all 24 reads are
//    base + compile-time immediate (row&7 == r16&7, so the XOR-swizzle
//    term is lane-constant; phase/m2/ni terms are literals).
//  * XCD swizzle: XCD k owns M-stripe [8k,8k+8) x all 12 N-tiles.
// ---------------------------------------------------------------------------
template<bool OUTBF>
__global__ __launch_bounds__(512, 2) void gemm256_kernel(
    const u16* __restrict__ A1, int lda1, int kt1,
    const u16* __restrict__ A2, int lda2, int kt2,
    const u16* __restrict__ B1, int ldb1,
    const u16* __restrict__ B2, int ldb2,
    void* __restrict__ outv, int ldo,
    const int* __restrict__ flag, int want)
{
    if (*flag != want) return;
    extern __shared__ short smem[];   // bytes: A dbuf [0,65536), B dbuf [65536,131072)

    const int tid  = threadIdx.x;
    const int lane = tid & 63;
    const int wave = tid >> 6;        // 0..7
    const int wm   = wave >> 2;       // 0..1
    const int wn   = wave & 3;        // 0..3
    const int quad = lane >> 4;
    const int r16  = lane & 15;
    const int rb   = lane >> 3;       // DMA: row-in-8
    const int swz  = (lane & 7) ^ rb; // DMA: pre-swizzled source chunk

    // XCD-aware mapping: xcd = lin&7 under round-robin dispatch; each XCD
    // gets M-stripe [8*xcd, 8*xcd+8) x all 12 N-tiles (bijective, 768 blocks)
    const int lin = blockIdx.y * 64 + blockIdx.x;
    const int xk  = lin & 7;
    const int j   = lin >> 3;                 // 0..95
    const int rowA0 = (xk * 8 + (j & 7)) * 256;
    const int rowB0 = (j >> 3) * 256;

    floatx4 acc[8][4];
#pragma unroll
    for (int mi = 0; mi < 8; ++mi)
#pragma unroll
        for (int ni = 0; ni < 4; ++ni)
            acc[mi][ni] = (floatx4){0.f, 0.f, 0.f, 0.f};

    // lane-constant ds_read byte offsets (swizzle term: row&7 == r16&7)
    const int sx    = r16 & 7;
    const int q0    = quad ^ sx;
    const int aoff0 = (wm * 128 + r16) * 128 + q0 * 16;
    const int aoff1 = (wm * 128 + r16) * 128 + (q0 ^ 4) * 16;
    const int boff0 = (wn * 64 + r16) * 128 + q0 * 16;
    const int boff1 = (wn * 64 + r16) * 128 + (q0 ^ 4) * 16;

    // per-lane incremental staging pointers (4 A slots + 4 B slots)
    const u16 *pA[4], *pB[4];
    int rA[4], rB[4];
#pragma unroll
    for (int i = 0; i < 4; ++i) {
        rA[i] = rowA0 + (i * 8 + wave) * 8 + rb;
        rB[i] = rowB0 + (i * 8 + wave) * 8 + rb;
        pA[i] = A1 + (size_t)rA[i] * lda1 + swz * 8;
        pB[i] = B1 + (size_t)rB[i] * ldb1 + swz * 8;
    }

    auto stA = [&](int nb, int i) {
        gload16(pA[i], smem + nb * 16384 + (i * 8 + wave) * 512);
        pA[i] += 64;
    };
    auto stB = [&](int nb, int i) {
        gload16(pB[i], smem + 32768 + nb * 16384 + (i * 8 + wave) * 512);
        pB[i] += 64;
    };

    // prologue: fully stage tile 0 into buffer 0
    stB(0, 0); stB(0, 1); stB(0, 2); stB(0, 3);
    stA(0, 0); stA(0, 1); stA(0, 2); stA(0, 3);
    asm volatile("s_waitcnt vmcnt(0)" ::: "memory");
    BARR;

    int cur = 0;
    short8 bf[4][2];
    const int ktot = kt1 + kt2;

    for (int kt = 0; kt < ktot; ++kt) {
        const int  ks   = kt + 1;
        const bool more = ks < ktot;
        const int  nb   = cur ^ 1;

        if (kt2 > 0 && ks == kt1) {           // one-time staging source switch
#pragma unroll
            for (int i = 0; i < 4; ++i) {
                pA[i] = A2 + (size_t)rA[i] * lda2 + swz * 8;
                pB[i] = B2 + (size_t)rB[i] * ldb2 + swz * 8;
            }
        }

        const char* sb   = (const char*)smem + cur * 32768;
        const char* pa0c = sb + aoff0;
        const char* pa1c = sb + aoff1;
        const char* pb0c = sb + 65536 + boff0;
        const char* pb1c = sb + 65536 + boff1;

        auto domfma = [&](int p, short8 af[2][2]) {
#pragma unroll
            for (int m2 = 0; m2 < 2; ++m2)
#pragma unroll
                for (int kx = 0; kx < 2; ++kx)
#pragma unroll
                    for (int ni = 0; ni < 4; ++ni)
                        acc[2 * p + m2][ni] = __builtin_amdgcn_mfma_f32_16x16x32_bf16(
                            af[m2][kx], bf[ni][kx], acc[2 * p + m2][ni], 0, 0, 0);
        };

        short8 af[2][2];

        // ---- phase 0: read A rows [0,32)+wm*128 and all B frags; stage B0,B1
#pragma unroll
        for (int m2 = 0; m2 < 2; ++m2) {
            af[m2][0] = *(const short8*)(pa0c + m2 * 2048);
            af[m2][1] = *(const short8*)(pa1c + m2 * 2048);
        }
#pragma unroll
        for (int ni = 0; ni < 4; ++ni) {
            bf[ni][0] = *(const short8*)(pb0c + ni * 2048);
            bf[ni][1] = *(const short8*)(pb1c + ni * 2048);
        }
        if (more) { stB(nb, 0); stB(nb, 1); }
        BARR; LGKM0;
        __builtin_amdgcn_s_setprio(1);
        domfma(0, af);
        __builtin_amdgcn_s_setprio(0);
        BARR;

        // ---- phase 1: stage B2,B3 + A0,A2; confirm prev tile's late A
#pragma unroll
        for (int m2 = 0; m2 < 2; ++m2) {
            af[m2][0] = *(const short8*)(pa0c + (2 + m2) * 2048);
            af[m2][1] = *(const short8*)(pa1c + (2 + m2) * 2048);
        }
        if (more) {
            stB(nb, 2); stB(nb, 3);
            stA(nb, 0); stA(nb, 2);
            asm volatile("s_waitcnt vmcnt(6)" ::: "memory");
        } else {
            asm volatile("s_waitcnt vmcnt(0)" ::: "memory");
        }
        BARR; LGKM0;
        __builtin_amdgcn_s_setprio(1);
        domfma(1, af);
        __builtin_amdgcn_s_setprio(0);
        BARR;

        // ---- phase 2: stage A1,A3
#pragma unroll
        for (int m2 = 0; m2 < 2; ++m2) {
            af[m2][0] = *(const short8*)(pa0c + (4 + m2) * 2048);
            af[m2][1] = *(const short8*)(pa1c + (4 + m2) * 2048);
        }
        if (more) { stA(nb, 1); stA(nb, 3); }
        BARR; LGKM0;
        __builtin_amdgcn_s_setprio(1);
        domfma(2, af);
        __builtin_amdgcn_s_setprio(0);
        BARR;

        // ---- phase 3: confirm B + early-A of next tile
#pragma unroll
        for (int m2 = 0; m2 < 2; ++m2) {
            af[m2][0] = *(const short8*)(pa0c + (6 + m2) * 2048);
            af[m2][1] = *(const short8*)(pa1c + (6 + m2) * 2048);
        }
        if (more) asm volatile("s_waitcnt vmcnt(2)" ::: "memory");
        BARR; LGKM0;
        __builtin_amdgcn_s_setprio(1);
        domfma(3, af);
        __builtin_amdgcn_s_setprio(0);
        BARR;

        cur = nb;
    }

    // epilogue: C/D layout col = lane&15, row = quad*4+reg
#pragma unroll
    for (int mi = 0; mi < 8; ++mi) {
#pragma unroll
        for (int r = 0; r < 4; ++r) {
            const int t = rowA0 + wm * 128 + mi * 16 + quad * 4 + r;
#pragma unroll
            for (int ni = 0; ni < 4; ++ni) {
                const int o = rowB0 + wn * 64 + ni * 16 + r16;
                float v = acc[mi][ni][r];
                if constexpr (OUTBF)
                    ((u16*)outv)[(size_t)t * ldo + o] = f2bf(v);
                else
                    ((float*)outv)[(size_t)t * ldo + o] = v;
            }
        }
    }
}

// ---------------------------------------------------------------------------
extern "C" void kernel_launch(void* const* d_in, const int* in_sizes, int n_in,
                              void* d_out, int out_size, void* d_ws, size_t ws_size,
                              hipStream_t stream)
{
    const void* x      = d_in[0];   // [T, D]
    const void* W      = d_in[1];   // [O, D]
    const void* gate_w = d_in[2];   // [E, D]
    const void* lora_A = d_in[3];   // [E*R, D]
    const void* lora_B = d_in[4];   // [E, O, R]

    int*   flag     = (int*)d_ws;
    float* s_te     = (float*)((char*)d_ws + 1024);
    u16*   a_scaled = (u16*)((char*)d_ws + 1024 + 524288);                 // [T, 256] bf16
    u16*   B_pack   = (u16*)((char*)d_ws + 1024 + 524288 + 8388608);       // [O, 256] bf16
    const size_t base_sz = 1024 + 524288 + 8388608 + 1572864;

    const size_t x16_sz = (size_t)T_NUM * D_DIM * 2;
    const size_t W16_sz = (size_t)O_DIM * D_DIM * 2;
    const size_t A16_sz = (size_t)KA * D_DIM * 2;
    const bool big = ws_size >= base_sz + x16_sz + W16_sz + A16_sz;
    u16* x16 = big ? (u16*)((char*)d_ws + base_sz) : nullptr;
    u16* W16 = big ? (u16*)((char*)x16 + x16_sz)   : nullptr;
    u16* A16 = big ? (u16*)((char*)W16 + W16_sz)   : nullptr;

    // opt-in to 128 KiB dynamic LDS for the 256^2 kernel (idempotent)
    (void)hipFuncSetAttribute((const void*)gemm256_kernel<true>,
                              hipFuncAttributeMaxDynamicSharedMemorySize, 131072);
    (void)hipFuncSetAttribute((const void*)gemm256_kernel<false>,
                              hipFuncAttributeMaxDynamicSharedMemorySize, 131072);

    detect_kernel<<<1, 1024, 0, stream>>>((const u16*)x, flag);

    routing_kernel<true ><<<T_NUM / 4, 256, 0, stream>>>(x, gate_w, s_te, nullptr, flag, 1);
    routing_kernel<false><<<T_NUM / 4, 256, 0, stream>>>(x, gate_w, s_te, x16, flag, 0);

    pack_b_kernel<true ><<<(E_NUM * O_DIM) / 256, 256, 0, stream>>>(lora_B, B_pack, flag, 1);
    pack_b_kernel<false><<<(E_NUM * O_DIM) / 256, 256, 0, stream>>>(lora_B, B_pack, flag, 0);

    const dim3 g2(T_NUM / 256, O_DIM / 256);   // 64 x 12

    // -------- flag==1 (inputs already bf16) --------------------------------
    gemm_kernel<true, true><<<dim3(T_NUM / 128, KA / 128), 256, 0, stream>>>(
        x, D_DIM, D_DIM / 64, (const u16*)x, D_DIM, 0,
        lora_A, D_DIM, (const u16*)lora_A, D_DIM,
        a_scaled, KA, s_te, 1, flag, 1);
    gemm256_kernel<true><<<g2, 512, 131072, stream>>>(
        (const u16*)x, D_DIM, D_DIM / 64, a_scaled, KA, KA / 64,
        (const u16*)W, D_DIM, B_pack, KA,
        d_out, O_DIM, flag, 1);

    // -------- flag==0 (fp32 inputs) ----------------------------------------
    if (big) {
        cvt_kernel<<<(O_DIM * D_DIM / 8 + 255) / 256, 256, 0, stream>>>(
            (const float*)W, W16, O_DIM * D_DIM / 8, flag, 0);
        cvt_kernel<<<(KA * D_DIM / 8 + 255) / 256, 256, 0, stream>>>(
            (const float*)lora_A, A16, KA * D_DIM / 8, flag, 0);

        gemm_kernel<true, true><<<dim3(T_NUM / 128, KA / 128), 256, 0, stream>>>(
            x16, D_DIM, D_DIM / 64, x16, D_DIM, 0,
            A16, D_DIM, A16, D_DIM,
            a_scaled, KA, s_te, 1, flag, 0);
        gemm256_kernel<false><<<g2, 512, 131072, stream>>>(
            x16, D_DIM, D_DIM / 64, a_scaled, KA, KA / 64,
            W16, D_DIM, B_pack, KA,
            d_out, O_DIM, flag, 0);
    } else {
        gemm_kernel<false, true><<<dim3(T_NUM / 128, KA / 128), 256, 0, stream>>>(
            x, D_DIM, D_DIM / 64, (const u16*)x, D_DIM, 0,
            lora_A, D_DIM, (const u16*)lora_A, D_DIM,
            a_scaled, KA, s_te, 1, flag, 0);
        gemm_kernel<false, false><<<dim3(T_NUM / 128, O_DIM / 128), 256, 0, stream>>>(
            x, D_DIM, D_DIM / 64, a_scaled, KA, 4,
            W, D_DIM, B_pack, KA,
            d_out, O_DIM, nullptr, 0, flag, 0);
    }
}